// Round 14
// baseline (270.308 us; speedup 1.0000x reference)
//
#include <hip/hip_runtime.h>
#include <cstdint>
#include <cstddef>

#define NN 50000
#define NE 1600000
#define ET (NE + NN)          // edges + self loops
#define NG 64
#define SCAN_BLOCKS ((NN + 255) / 256)   // 196
#define NB ((NN + 127) >> 7)             // 391 dst-buckets, 128 nodes each
#define EPT 16
#define EPB (256 * EPT)                  // 4096 edges per bin-block
#define BIN_BLOCKS ((ET + EPB - 1) / EPB)

// ---------------- K0: transpose W1 [512][64] -> Wt2 k-packed float4
__global__ void k_wt(const float* __restrict__ W1, float* __restrict__ Wt2) {
    int id = blockIdx.x * 256 + threadIdx.x;
    if (id >= 128 * 64) return;
    int k4 = id >> 6, c = id & 63;
    float4 v;
    v.x = W1[(k4 * 4 + 0) * 64 + c];
    v.y = W1[(k4 * 4 + 1) * 64 + c];
    v.z = W1[(k4 * 4 + 2) * 64 + c];
    v.w = W1[(k4 * 4 + 3) * 64 + c];
    reinterpret_cast<float4*>(Wt2)[id] = v;
}

// ---------------- K1: h1 = x @ W1, full-K, 32 rows/block, LDS-staged 8 phases.
// Fused as1/ad1 epilogue (shfl_xor reduce over 8-channel groups).
__global__ __launch_bounds__(256, 8) void k_gemm1(
    const float* __restrict__ x, const float* __restrict__ Wt2,
    const float* __restrict__ aS, const float* __restrict__ aD,
    float* __restrict__ h1, float* __restrict__ as1, float* __restrict__ ad1) {
    __shared__ float4 xs[32 * 16];    // 8 KB
    __shared__ float4 wsr[16 * 64];   // 16 KB

    int t = threadIdx.x;
    int lane = t & 63, wv_id = t >> 6;
    int n0 = blockIdx.x * 32;

    const float4* __restrict__ xf = reinterpret_cast<const float4*>(x);
    const float4* __restrict__ wf = reinterpret_cast<const float4*>(Wt2);

    int tc = t & 15;
    int trg = t >> 4;                 // 0..15; rows trg, trg+16
    int swz = (trg & 3) << 1;

    float acc[2][4];
#pragma unroll
    for (int i = 0; i < 2; ++i)
#pragma unroll
        for (int j = 0; j < 4; ++j) acc[i][j] = 0.f;

    for (int ph = 0; ph < 8; ++ph) {
        int kb4 = ph * 16;
        // stage x: 512 slots; swizzled global source, linear LDS dest (rule #21)
#pragma unroll
        for (int q = 0; q < 2; ++q) {
            int base = (wv_id * 2 + q) * 64;
            int s = base + lane;
            int row = s >> 4;
            int m = s & 15;
            int k4f = m ^ ((row & 3) << 1);
            int rr = n0 + row; if (rr >= NN) rr = NN - 1;
            const float4* src = xf + (size_t)rr * 128 + kb4 + k4f;
            __builtin_amdgcn_global_load_lds(
                (const __attribute__((address_space(1))) void*)src,
                (__attribute__((address_space(3))) void*)&xs[base], 16, 0, 0);
        }
        // stage W: 1024 slots, linear
#pragma unroll
        for (int q = 0; q < 4; ++q) {
            int base = (wv_id * 4 + q) * 64;
            int s = base + lane;
            int k4 = s >> 6, c = s & 63;
            const float4* src = wf + (size_t)(kb4 + k4) * 64 + c;
            __builtin_amdgcn_global_load_lds(
                (const __attribute__((address_space(1))) void*)src,
                (__attribute__((address_space(3))) void*)&wsr[base], 16, 0, 0);
        }
        __syncthreads();

#pragma unroll 2
        for (int k4 = 0; k4 < 16; ++k4) {
            float4 wv0 = wsr[k4 * 64 + tc];
            float4 wv1 = wsr[k4 * 64 + tc + 16];
            float4 wv2 = wsr[k4 * 64 + tc + 32];
            float4 wv3 = wsr[k4 * 64 + tc + 48];
            int kx = k4 ^ swz;
            float4 xv0 = xs[trg * 16 + kx];
            float4 xv1 = xs[(trg + 16) * 16 + kx];
#define FMA4(a, xv, wv) { a += xv.x * wv.x; a += xv.y * wv.y; a += xv.z * wv.z; a += xv.w * wv.w; }
            FMA4(acc[0][0], xv0, wv0) FMA4(acc[0][1], xv0, wv1) FMA4(acc[0][2], xv0, wv2) FMA4(acc[0][3], xv0, wv3)
            FMA4(acc[1][0], xv1, wv0) FMA4(acc[1][1], xv1, wv1) FMA4(acc[1][2], xv1, wv2) FMA4(acc[1][3], xv1, wv3)
#undef FMA4
        }
        __syncthreads();   // protect LDS before next phase's staging
    }

    // epilogue: store h1 (cols tc+16j) + fused as1/ad1
    int hb = tc >> 3;        // 0 or 1: heads 2j+hb
    int cc = tc & 7;         // channel within head
#pragma unroll
    for (int i = 0; i < 2; ++i) {
        int r = n0 + trg + 16 * i;
        if (r >= NN) continue;
        float* rowp = h1 + (size_t)r * 64 + tc;
        rowp[0]  = acc[i][0];
        rowp[16] = acc[i][1];
        rowp[32] = acc[i][2];
        rowp[48] = acc[i][3];

        float ps[4], pd[4];
#pragma unroll
        for (int j = 0; j < 4; ++j) {
            int h = 2 * j + hb;
            ps[j] = acc[i][j] * aS[h * 8 + cc];
            pd[j] = acc[i][j] * aD[h * 8 + cc];
        }
#pragma unroll
        for (int ofs = 1; ofs <= 4; ofs <<= 1) {
#pragma unroll
            for (int j = 0; j < 4; ++j) {
                ps[j] += __shfl_xor(ps[j], ofs);
                pd[j] += __shfl_xor(pd[j], ofs);
            }
        }
        if (cc == 0) {
#pragma unroll
            for (int j = 0; j < 4; ++j) {
                int h = 2 * j + hb;
                as1[r * 8 + h] = ps[j];
                ad1[r * 8 + h] = pd[j];
            }
        }
    }
}

// ---------------- CSR build: bhist -> bscan -> bin -> bdeg -> scan -> unbin
__global__ __launch_bounds__(256) void k_bhist(const int* __restrict__ edst, int* __restrict__ bdeg) {
    __shared__ int cnt[NB];
    int tid = threadIdx.x;
    for (int b = tid; b < NB; b += 256) cnt[b] = 0;
    __syncthreads();
    int e0 = blockIdx.x * EPB;
#pragma unroll
    for (int q = 0; q < EPT; ++q) {
        int e = e0 + q * 256 + tid;
        if (e < ET) {
            int d = (e < NE) ? edst[e] : (e - NE);
            atomicAdd(&cnt[d >> 7], 1);
        }
    }
    __syncthreads();
    for (int b = tid; b < NB; b += 256)
        if (cnt[b]) atomicAdd(&bdeg[b], cnt[b]);
}

__global__ __launch_bounds__(512) void k_bscan(const int* __restrict__ bdeg,
                                               int* __restrict__ bo, int* __restrict__ bcur) {
    __shared__ int lds_w[8];
    int tid = threadIdx.x;
    int lane = tid & 63, wid = tid >> 6;
    int v = (tid < NB) ? bdeg[tid] : 0;
    int incl = v;
#pragma unroll
    for (int ofs = 1; ofs < 64; ofs <<= 1) {
        int o = __shfl_up(incl, ofs);
        if (lane >= ofs) incl += o;
    }
    if (lane == 63) lds_w[wid] = incl;
    __syncthreads();
    int wadd = 0;
    for (int w = 0; w < wid; ++w) wadd += lds_w[w];
    incl += wadd;
    int ex = incl - v;
    if (tid < NB) { bo[tid] = ex; bcur[tid] = ex; }
    if (tid == NB - 1) bo[NB] = ex + v;   // == ET
}

__global__ __launch_bounds__(256) void k_bin(
    const int* __restrict__ esrc, const int* __restrict__ edst,
    int* __restrict__ bcur, uint2* __restrict__ rec) {
    __shared__ int bcnt[NB];
    int tid = threadIdx.x;
    for (int b = tid; b < NB; b += 256) bcnt[b] = 0;
    __syncthreads();
    int e0 = blockIdx.x * EPB;
    uint2 rv[EPT]; int rk[EPT];
#pragma unroll
    for (int q = 0; q < EPT; ++q) {
        int e = e0 + q * 256 + tid;
        rk[q] = -1;
        if (e < ET) {
            int s, d;
            if (e < NE) { s = esrc[e]; d = edst[e]; } else { s = d = e - NE; }
            rv[q] = make_uint2((unsigned)s, (unsigned)d);
            rk[q] = atomicAdd(&bcnt[d >> 7], 1);
        }
    }
    __syncthreads();
    for (int b = tid; b < NB; b += 256)
        bcnt[b] = atomicAdd(&bcur[b], bcnt[b]);
    __syncthreads();
#pragma unroll
    for (int q = 0; q < EPT; ++q) {
        if (rk[q] >= 0) rec[bcnt[rv[q].y >> 7] + rk[q]] = rv[q];
    }
}

__global__ __launch_bounds__(256) void k_bdeg(const int* __restrict__ bo, const uint2* __restrict__ rec,
                                              int* __restrict__ deg) {
    __shared__ int cnt[128];
    int b = blockIdx.x, tid = threadIdx.x;
    if (tid < 128) cnt[tid] = 0;
    __syncthreads();
    int lo = bo[b], hi = bo[b + 1];
    for (int i = lo + tid; i < hi; i += 256)
        atomicAdd(&cnt[rec[i].y & 127], 1);
    __syncthreads();
    if (tid < 128) {
        int n = (b << 7) + tid;
        if (n < NN) deg[n] = cnt[tid];
    }
}

__global__ __launch_bounds__(256) void k_scan1(const int* __restrict__ deg,
                                               int* __restrict__ offs, int* __restrict__ bsum) {
    __shared__ int lds_w[4];
    int i = blockIdx.x * 256 + threadIdx.x;
    int v = (i < NN) ? deg[i] : 0;
    int lane = threadIdx.x & 63, wid = threadIdx.x >> 6;
    int incl = v;
#pragma unroll
    for (int ofs = 1; ofs < 64; ofs <<= 1) {
        int o = __shfl_up(incl, ofs);
        if (lane >= ofs) incl += o;
    }
    if (lane == 63) lds_w[wid] = incl;
    __syncthreads();
    int wadd = 0;
    for (int w = 0; w < wid; ++w) wadd += lds_w[w];
    incl += wadd;
    if (i < NN) offs[i] = incl - v;
    if (threadIdx.x == 255) bsum[blockIdx.x] = incl;
}

__global__ void k_scan2(const int* __restrict__ bsum, int* __restrict__ bpre) {
    __shared__ int lds_w[4];
    int lane = threadIdx.x & 63, wid = threadIdx.x >> 6;
    int v = (threadIdx.x < SCAN_BLOCKS) ? bsum[threadIdx.x] : 0;
    int incl = v;
#pragma unroll
    for (int ofs = 1; ofs < 64; ofs <<= 1) {
        int o = __shfl_up(incl, ofs);
        if (lane >= ofs) incl += o;
    }
    if (lane == 63) lds_w[wid] = incl;
    __syncthreads();
    int wadd = 0;
    for (int w = 0; w < wid; ++w) wadd += lds_w[w];
    incl += wadd;
    bpre[threadIdx.x] = incl - v;
}

__global__ void k_scan3(int* __restrict__ offs, const int* __restrict__ bpre) {
    int i = blockIdx.x * 256 + threadIdx.x;
    if (i < NN) offs[i] = offs[i] + bpre[blockIdx.x];
    if (i == 0) offs[NN] = ET;
}

__global__ __launch_bounds__(256) void k_unbin(
    const int* __restrict__ offs, const int* __restrict__ bo,
    const uint2* __restrict__ rec, int* __restrict__ csr) {
    __shared__ int lcur[128];
    int b = blockIdx.x, tid = threadIdx.x;
    if (tid < 128) {
        int n = (b << 7) + tid;
        lcur[tid] = (n < NN) ? offs[n] : 0;
    }
    __syncthreads();
    int lo = bo[b], hi = bo[b + 1];
    for (int i = lo + tid; i < hi; i += 256) {
        uint2 r = rec[i];
        int pos = atomicAdd(&lcur[r.y & 127], 1);
        csr[pos] = (int)r.x;
    }
}

// ---------------- K4: layer-1 aggregation. Wave per dst; lane = (slot g = l>>4, f4 q = l&15).
__global__ __launch_bounds__(256) void k_agg1(
    const int* __restrict__ offs, const int* __restrict__ csr,
    const float* __restrict__ h1, const float* __restrict__ as1, const float* __restrict__ ad1,
    const float* __restrict__ bias1, float* __restrict__ h1o) {
    int l = threadIdx.x & 63;
    int dst = blockIdx.x * 4 + (threadIdx.x >> 6);
    if (dst >= NN) return;
    int g = l >> 4;            // edge slot 0..3
    int q = l & 15;            // float4 index in 64-ch row
    int h = q >> 1;            // head
    int beg = offs[dst], end = offs[dst + 1];
    int lastj = end - 1;       // deg >= 1 (self-loop)
    float adh = ad1[dst * 8 + h];
    const float4* __restrict__ h1f = reinterpret_cast<const float4*>(h1);

    float4 acc = make_float4(0.f, 0.f, 0.f, 0.f);
    float dsum = 0.f;

    int sA[4], sB[4];
#pragma unroll
    for (int p = 0; p < 4; ++p) sA[p] = csr[min(beg + p * 4 + g, lastj)];
    for (int j = beg; j < end; j += 16) {
#pragma unroll
        for (int p = 0; p < 4; ++p) sB[p] = csr[min(j + 16 + p * 4 + g, lastj)];
        float av[4]; float4 vv[4];
#pragma unroll
        for (int p = 0; p < 4; ++p) {
            av[p] = as1[sA[p] * 8 + h];
            vv[p] = h1f[sA[p] * 16 + q];
        }
#pragma unroll
        for (int p = 0; p < 4; ++p) {
            float e = av[p] + adh; e = (e > 0.f) ? e : 0.2f * e;
            float w = __expf(e);
            w = (j + p * 4 + g < end) ? w : 0.f;
            acc.x += w * vv[p].x; acc.y += w * vv[p].y;
            acc.z += w * vv[p].z; acc.w += w * vv[p].w;
            dsum += w;
        }
#pragma unroll
        for (int p = 0; p < 4; ++p) sA[p] = sB[p];
    }

#pragma unroll
    for (int ofs = 16; ofs <= 32; ofs <<= 1) {
        acc.x += __shfl_xor(acc.x, ofs);
        acc.y += __shfl_xor(acc.y, ofs);
        acc.z += __shfl_xor(acc.z, ofs);
        acc.w += __shfl_xor(acc.w, ofs);
        dsum  += __shfl_xor(dsum, ofs);
    }

    if (g == 0) {
        float inv = 1.f / (dsum + 1e-16f);
        const float4 bq = reinterpret_cast<const float4*>(bias1)[q];
        float4 r;
        r.x = acc.x * inv + bq.x;
        r.y = acc.y * inv + bq.y;
        r.z = acc.z * inv + bq.z;
        r.w = acc.w * inv + bq.w;
        r.x = (r.x > 0.f) ? r.x : (__expf(r.x) - 1.f);
        r.y = (r.y > 0.f) ? r.y : (__expf(r.y) - 1.f);
        r.z = (r.z > 0.f) ? r.z : (__expf(r.z) - 1.f);
        r.w = (r.w > 0.f) ? r.w : (__expf(r.w) - 1.f);
        reinterpret_cast<float4*>(h1o)[dst * 16 + q] = r;
    }
}

// ---------------- K6: h2 = h1o @ W2 (+ alpha2 reductions). 32 lanes per node.
__global__ __launch_bounds__(256) void k_gemm2(
    const float* __restrict__ h1o, const float* __restrict__ W2,
    const float* __restrict__ aS, const float* __restrict__ aD,
    float* __restrict__ h2, float* __restrict__ as2, float* __restrict__ ad2) {
    int c = threadIdx.x & 31;
    int n = blockIdx.x * 8 + (threadIdx.x >> 5);
    if (n >= NN) return;
    const float4* hf = reinterpret_cast<const float4*>(h1o + n * 64);
    float acc = 0.f;
#pragma unroll
    for (int k4 = 0; k4 < 16; ++k4) {
        float4 hv = hf[k4];
        acc += hv.x * W2[(k4 * 4 + 0) * 32 + c] + hv.y * W2[(k4 * 4 + 1) * 32 + c] +
               hv.z * W2[(k4 * 4 + 2) * 32 + c] + hv.w * W2[(k4 * 4 + 3) * 32 + c];
    }
    h2[n * 32 + c] = acc;
    float ps = acc * aS[c], pd = acc * aD[c];
#pragma unroll
    for (int o = 1; o < 32; o <<= 1) { ps += __shfl_xor(ps, o); pd += __shfl_xor(pd, o); }
    if (c == 0) { as2[n] = ps; ad2[n] = pd; }
}

// ---------------- K7: layer-2 aggregation. Wave per dst; lane = (slot g = l>>3, f4 q = l&7).
__global__ __launch_bounds__(256) void k_agg2(
    const int* __restrict__ offs, const int* __restrict__ csr,
    const float* __restrict__ h2, const float* __restrict__ as2, const float* __restrict__ ad2,
    const float* __restrict__ bias2, float* __restrict__ o2) {
    int l = threadIdx.x & 63;
    int dst = blockIdx.x * 4 + (threadIdx.x >> 6);
    if (dst >= NN) return;
    int g = l >> 3;            // edge slot 0..7
    int q = l & 7;             // float4 index in 32-ch row
    int beg = offs[dst], end = offs[dst + 1];
    int lastj = end - 1;
    float adh = ad2[dst];
    const float4* __restrict__ h2f = reinterpret_cast<const float4*>(h2);

    float4 acc = make_float4(0.f, 0.f, 0.f, 0.f);
    float dsum = 0.f;

    int sA[4], sB[4];
#pragma unroll
    for (int p = 0; p < 4; ++p) sA[p] = csr[min(beg + p * 8 + g, lastj)];
    for (int j = beg; j < end; j += 32) {
#pragma unroll
        for (int p = 0; p < 4; ++p) sB[p] = csr[min(j + 32 + p * 8 + g, lastj)];
        float av[4]; float4 vv[4];
#pragma unroll
        for (int p = 0; p < 4; ++p) {
            av[p] = as2[sA[p]];
            vv[p] = h2f[sA[p] * 8 + q];
        }
#pragma unroll
        for (int p = 0; p < 4; ++p) {
            float e = av[p] + adh; e = (e > 0.f) ? e : 0.2f * e;
            float w = __expf(e);
            w = (j + p * 8 + g < end) ? w : 0.f;
            acc.x += w * vv[p].x; acc.y += w * vv[p].y;
            acc.z += w * vv[p].z; acc.w += w * vv[p].w;
            dsum += w;
        }
#pragma unroll
        for (int p = 0; p < 4; ++p) sA[p] = sB[p];
    }

#pragma unroll
    for (int ofs = 8; ofs <= 32; ofs <<= 1) {
        acc.x += __shfl_xor(acc.x, ofs);
        acc.y += __shfl_xor(acc.y, ofs);
        acc.z += __shfl_xor(acc.z, ofs);
        acc.w += __shfl_xor(acc.w, ofs);
        dsum  += __shfl_xor(dsum, ofs);
    }

    if (g == 0) {
        float inv = 1.f / (dsum + 1e-16f);
        const float4 bq = reinterpret_cast<const float4*>(bias2)[q];
        float4 r;
        r.x = acc.x * inv + bq.x;
        r.y = acc.y * inv + bq.y;
        r.z = acc.z * inv + bq.z;
        r.w = acc.w * inv + bq.w;
        reinterpret_cast<float4*>(o2)[dst * 8 + q] = r;
    }
}

// ---------------- K8: graph boundaries from sorted batch.
__global__ void k_bound(const int* __restrict__ batch, int* __restrict__ lo) {
    int n = blockIdx.x * 256 + threadIdx.x;
    if (n >= NN) return;
    int b = batch[n];
    if (n == 0) {
        for (int g = 0; g <= b; ++g) lo[g] = 0;
    } else {
        int pb = batch[n - 1];
        for (int g = pb + 1; g <= b; ++g) lo[g] = n;
    }
    if (n == NN - 1) {
        for (int g = b + 1; g <= NG; ++g) lo[g] = NN;
    }
}

// ---------------- K9: pooled sums.
__global__ __launch_bounds__(256) void k_pool(const float* __restrict__ o2, const int* __restrict__ lo,
                                              float* __restrict__ pooled) {
    __shared__ float red[256];
    int g = blockIdx.x & 63, q = blockIdx.x >> 6;
    int beg = lo[g], end = lo[g + 1];
    int c = threadIdx.x & 31, row = threadIdx.x >> 5;
    float s = 0.f;
    for (int n = beg + q * 8 + row; n < end; n += 32) s += o2[n * 32 + c];
    red[threadIdx.x] = s;
    __syncthreads();
    for (int rr = 4; rr >= 1; rr >>= 1) {
        if (row < rr) red[threadIdx.x] += red[(row + rr) * 32 + c];
        __syncthreads();
    }
    if (row == 0) atomicAdd(&pooled[g * 32 + c], red[c]);
}

// ---------------- K10: mean + final linear -> out[64][2]
__global__ void k_fin(const float* __restrict__ pooled, const int* __restrict__ lo,
                      const float* __restrict__ lw, const float* __restrict__ lb,
                      float* __restrict__ out) {
    int t = threadIdx.x;
    if (t >= 128) return;
    int g = t >> 1, o = t & 1;
    int cnt = lo[g + 1] - lo[g];
    float inv = 1.f / fmaxf((float)cnt, 1.f);
    float s = 0.f;
#pragma unroll
    for (int c = 0; c < 32; ++c) s += pooled[g * 32 + c] * lw[c * 2 + o];
    out[g * 2 + o] = s * inv + lb[o];
}

// ----------------------------------------------------------------------------
extern "C" void kernel_launch(void* const* d_in, const int* in_sizes, int n_in,
                              void* d_out, int out_size, void* d_ws, size_t ws_size,
                              hipStream_t stream) {
    const float* x   = (const float*)d_in[0];
    const int*   ei  = (const int*)d_in[1];     // [2][NE]
    const int*   bat = (const int*)d_in[2];
    const float* W1  = (const float*)d_in[3];
    const float* aS1 = (const float*)d_in[4];
    const float* aD1 = (const float*)d_in[5];
    const float* b1  = (const float*)d_in[6];
    const float* W2  = (const float*)d_in[7];
    const float* aS2 = (const float*)d_in[8];
    const float* aD2 = (const float*)d_in[9];
    const float* b2  = (const float*)d_in[10];
    const float* lw  = (const float*)d_in[11];
    const float* lb  = (const float*)d_in[12];
    float* out = (float*)d_out;

    const int* esrc = ei;
    const int* edst = ei + NE;

    char* ws = (char*)d_ws;
    size_t off = 0;
    auto alloc = [&](size_t bytes) -> void* {
        off = (off + 255) & ~(size_t)255;
        void* p = ws + off;
        off += bytes;
        return p;
    };

    float* regA = (float*)alloc((size_t)NN * 64 * 4);   // h1; later reused: h2 @ 0, o2 @ NN*32
    float* h1   = regA;
    float* h2   = regA;                                  // alias (h1 dead after k_agg1)
    float* o2   = regA + (size_t)NN * 32;                // alias
    float* h1o  = (float*)alloc((size_t)NN * 64 * 4);
    float* as1  = (float*)alloc((size_t)NN * 8 * 4);
    float* ad1  = (float*)alloc((size_t)NN * 8 * 4);
    float* as2  = (float*)alloc((size_t)NN * 4);
    float* ad2  = (float*)alloc((size_t)NN * 4);
    int*   offs = (int*)alloc((size_t)(NN + 1) * 4);
    int*   deg  = (int*)alloc((size_t)NN * 4);
    int*   csr  = (int*)alloc((size_t)ET * 4);
    uint2* rec  = (uint2*)alloc((size_t)ET * 8);
    int*   bdeg = (int*)alloc((size_t)NB * 4);
    int*   bo   = (int*)alloc((size_t)(NB + 1) * 4);
    int*   bcur = (int*)alloc((size_t)NB * 4);
    float* Wt2  = (float*)alloc((size_t)512 * 64 * 4);
    int*   bsum = (int*)alloc(256 * 4);
    int*   bpre = (int*)alloc(256 * 4);
    float* pooled = (float*)alloc((size_t)NG * 32 * 4);
    int*   lo   = (int*)alloc((size_t)(NG + 1) * 4);
    if (off > ws_size) return;   // workspace too small: leave d_out poisoned (visible failure)

    hipMemsetAsync(bdeg, 0, (size_t)NB * 4, stream);
    hipMemsetAsync(pooled, 0, (size_t)NG * 32 * 4, stream);

    k_wt<<<32, 256, 0, stream>>>(W1, Wt2);
    k_gemm1<<<(NN + 31) / 32, 256, 0, stream>>>(x, Wt2, aS1, aD1, h1, as1, ad1);

    k_bhist<<<BIN_BLOCKS, 256, 0, stream>>>(edst, bdeg);
    k_bscan<<<1, 512, 0, stream>>>(bdeg, bo, bcur);
    k_bin<<<BIN_BLOCKS, 256, 0, stream>>>(esrc, edst, bcur, rec);
    k_bdeg<<<NB, 256, 0, stream>>>(bo, rec, deg);
    k_scan1<<<SCAN_BLOCKS, 256, 0, stream>>>(deg, offs, bsum);
    k_scan2<<<1, 256, 0, stream>>>(bsum, bpre);
    k_scan3<<<SCAN_BLOCKS, 256, 0, stream>>>(offs, bpre);
    k_unbin<<<NB, 256, 0, stream>>>(offs, bo, rec, csr);

    k_agg1<<<(NN + 3) / 4, 256, 0, stream>>>(offs, csr, h1, as1, ad1, b1, h1o);
    k_gemm2<<<(NN + 7) / 8, 256, 0, stream>>>(h1o, W2, aS2, aD2, h2, as2, ad2);
    k_agg2<<<(NN + 3) / 4, 256, 0, stream>>>(offs, csr, h2, as2, ad2, b2, o2);

    k_bound<<<SCAN_BLOCKS, 256, 0, stream>>>(bat, lo);
    k_pool<<<NG * 4, 256, 0, stream>>>(o2, lo, pooled);
    k_fin<<<1, 128, 0, stream>>>(pooled, lo, lw, lb, out);
}